// Round 1
// 402.617 us; speedup vs baseline: 1.0744x; 1.0744x over previous
//
#include <hip/hip_runtime.h>

// ---------------------------------------------------------------------------
// GCN 2-layer fused pipeline for MI355X (gfx950)
//   h1 = relu(Dinv (A+I) Dinv (x@W1) + b1)
//   out = 0.5*(h1@Wc + bc) + 0.5*((alpha*h2 + (1-alpha)*h1)@Wf + bf)
//   h2 = relu(Dinv (A+I) Dinv (h1@W2) + b2)
// R2: binned counting-sort CSR. R3: fused dinv into colv. R5/R6: multi-edge
// wide gathers. R8: 1-dword colv (st<<15|w15), packed f32x2 agg math.
// R7 FAILED for gemm (LDS+barrier K-loop stays latency-bound at low
// occupancy: MfmaUtil 3%, 78us vs 16us HBM floor).
// R9: barrier-free register-pipelined GEMM (no LDS, no syncthreads).
// R10: agg restructured one-node-per-QUARTER (4 nodes/wave). Old layout was
// degree-capped at ~4 outstanding gathers/lane (avg deg 16 -> 4 t-groups) and
// duplicated epilogue across quarters. Now: per 16-edge chunk, issue ALL 16
// row-gathers per lane (depth-16 pipe, pf[16]), prefetch next colv word, then
// consume; quarter-local xor reduction (4 levels). Tests latency-vs-misspath
// theory: if dur unchanged, L2-miss path (MSHR/L3 random BW) is saturated.
// ---------------------------------------------------------------------------

#define HID 128
#define SHIFT 9
#define RANGE 512           // nodes per bin = 1<<SHIFT
#define MAXB 256            // max bins (N <= 131072)
#define TILE 4096           // edges per stage block

typedef __bf16 bf16x8 __attribute__((ext_vector_type(8)));
typedef float  f32x4  __attribute__((ext_vector_type(4)));
typedef float  f32x2  __attribute__((ext_vector_type(2)));

__device__ __forceinline__ unsigned short f2bf(float x) {
    unsigned int b = __float_as_uint(x);
    b += 0x7fffu + ((b >> 16) & 1u);     // round-to-nearest-even
    return (unsigned short)(b >> 16);
}
__device__ __forceinline__ float bflo(unsigned int u) { return __uint_as_float(u << 16); }
__device__ __forceinline__ float bfhi(unsigned int u) { return __uint_as_float(u & 0xffff0000u); }
__device__ __forceinline__ unsigned packbf(float a, float b) {
    return (unsigned)f2bf(a) | ((unsigned)f2bf(b) << 16);
}

// --------------------------- binned CSR build ------------------------------

__global__ __launch_bounds__(256)
void bincount_kernel(const int* __restrict__ dst, int* __restrict__ bin_counts,
                     int E, int NB) {
    __shared__ int h[MAXB];
    for (int i = threadIdx.x; i < NB; i += 256) h[i] = 0;
    __syncthreads();
    const int base = blockIdx.x * TILE;
#pragma unroll
    for (int j = 0; j < TILE; j += 256) {
        int e = base + j + threadIdx.x;
        if (e < E) atomicAdd(&h[((unsigned)dst[e]) >> SHIFT], 1);
    }
    __syncthreads();
    for (int i = threadIdx.x; i < NB; i += 256) {
        int v = h[i];
        if (v) atomicAdd(&bin_counts[i], v);
    }
}

__global__ void binscan_kernel(const int* __restrict__ bin_counts,
                               int* __restrict__ bin_off, int* __restrict__ bin_cur, int NB) {
    __shared__ int sh[MAXB];
    const int t = threadIdx.x;
    int v = (t < NB) ? bin_counts[t] : 0;
    sh[t] = v;
    __syncthreads();
    for (int s = 1; s < 256; s <<= 1) {
        int x = (t >= s) ? sh[t - s] : 0;
        __syncthreads();
        sh[t] += x;
        __syncthreads();
    }
    if (t < NB) {
        int ex = sh[t] - v;     // exclusive
        bin_off[t] = ex;
        bin_cur[t] = ex;
    }
}

// Block-level binning: tile-local LDS sort by bin, then bin-sorted write-out
// in contiguous runs. pairs[i] = (dlocal<<23) | src   (src < 2^23).
__global__ __launch_bounds__(256)
void stage_kernel(const int* __restrict__ src, const int* __restrict__ dst,
                  int* __restrict__ bin_cur, unsigned* __restrict__ pairs, int E) {
    __shared__ int sh_hist[MAXB];
    __shared__ int sh_off[MAXB];
    __shared__ int sh_ex[MAXB];
    __shared__ int sh_gbase[MAXB];
    __shared__ uint2 stg[TILE];
    const int t = threadIdx.x;
    const int base = blockIdx.x * TILE;
    const int cnt = min(TILE, E - base);

    for (int i = t; i < MAXB; i += 256) sh_hist[i] = 0;
    __syncthreads();

    int s[16], d[16], r[16];
#pragma unroll
    for (int j = 0; j < 16; ++j) {
        const int k = j * 256 + t;
        if (k < cnt) {
            s[j] = src[base + k];
            d[j] = dst[base + k];
            r[j] = atomicAdd(&sh_hist[((unsigned)d[j]) >> SHIFT], 1);
        }
    }
    __syncthreads();

    const int hv = sh_hist[t];
    sh_off[t] = hv;
    __syncthreads();
    for (int st = 1; st < 256; st <<= 1) {
        int x = (t >= st) ? sh_off[t - st] : 0;
        __syncthreads();
        sh_off[t] += x;
        __syncthreads();
    }
    sh_ex[t] = sh_off[t] - hv;                      // exclusive within tile
    if (hv > 0) sh_gbase[t] = atomicAdd(&bin_cur[t], hv);
    __syncthreads();

#pragma unroll
    for (int j = 0; j < 16; ++j) {
        const int k = j * 256 + t;
        if (k < cnt) {
            int b = ((unsigned)d[j]) >> SHIFT;
            stg[sh_ex[b] + r[j]] = make_uint2((unsigned)s[j], (unsigned)d[j]);
        }
    }
    __syncthreads();

    for (int i = t; i < cnt; i += 256) {
        uint2 p = stg[i];
        int b = (int)(p.y >> SHIFT);
        unsigned w = ((p.y & (RANGE - 1)) << 23) | p.x;
        pairs[sh_gbase[b] + (i - sh_ex[b])] = w;
    }
}

// Per-bin: histogram pairs -> counts; intra-bin scan (+bin_off base) -> rowp;
// dinv from counts.
__global__ __launch_bounds__(256)
void binrowp_kernel(const unsigned* __restrict__ pairs, const int* __restrict__ bin_off,
                    float* __restrict__ dinv, int* __restrict__ rowp,
                    int N, int NB, int E) {
    __shared__ int c[RANGE];
    __shared__ int sh[256];
    const int b = blockIdx.x;
    const int t = threadIdx.x;
    const int nb = b << SHIFT;
    const int nr = min(RANGE, N - nb);
    for (int i = t; i < RANGE; i += 256) c[i] = 0;
    __syncthreads();
    const int lo = bin_off[b];
    const int hi = (b + 1 < NB) ? bin_off[b + 1] : E;
    for (int i = lo + t; i < hi; i += 256)
        atomicAdd(&c[pairs[i] >> 23], 1);
    __syncthreads();
    const int v0 = c[2 * t], v1 = c[2 * t + 1];
    const int pr = v0 + v1;
    sh[t] = pr;
    __syncthreads();
    for (int s = 1; s < 256; s <<= 1) {
        int x = (t >= s) ? sh[t - s] : 0;
        __syncthreads();
        sh[t] += x;
        __syncthreads();
    }
    const int ex = sh[t] - pr + lo;     // exclusive prefix + bin edge base
    if (2 * t < nr) {
        rowp[nb + 2 * t] = ex;
        dinv[nb + 2 * t] = rsqrtf((float)(v0 + 1));
    }
    if (2 * t + 1 < nr) {
        rowp[nb + 2 * t + 1] = ex + v0;
        dinv[nb + 2 * t + 1] = rsqrtf((float)(v1 + 1));
    }
    if (b == 0 && t == 0) rowp[N] = E;
}

// Per-bin fine scatter; emits packed (src<<15)|fixed15(dinv[src])
__global__ __launch_bounds__(256)
void fine_kernel(const unsigned* __restrict__ pairs, const int* __restrict__ bin_off,
                 const int* __restrict__ rowp, const float* __restrict__ dinv,
                 unsigned* __restrict__ colv1, int N, int NB, int E) {
    __shared__ int cur[RANGE];
    const int b = blockIdx.x;
    const int nb = b << SHIFT;
    const int nr = min(RANGE, N - nb);
    for (int i = threadIdx.x; i < nr; i += 256) cur[i] = rowp[nb + i];
    __syncthreads();
    const int lo = bin_off[b];
    const int hi = (b + 1 < NB) ? bin_off[b + 1] : E;
    for (int i = lo + threadIdx.x; i < hi; i += 256) {
        unsigned w = pairs[i];
        unsigned s = w & 0x7fffffu;
        int pos = atomicAdd(&cur[w >> 23], 1);
        unsigned w15 = __float2uint_rn(dinv[s] * 32767.0f);   // dinv in (0,1]
        colv1[pos] = (s << 15) | w15;
    }
}

// Merged prep: zero bin_counts + both weight transposes (Wt[col][k] bf16)
__global__ void prep_kernel(const float* __restrict__ W1, const float* __restrict__ W2,
                            unsigned short* __restrict__ wt1, unsigned short* __restrict__ wt2,
                            int K1, int* __restrict__ bin_counts) {
    int idx = blockIdx.x * 256 + threadIdx.x;
    if (idx < MAXB) bin_counts[idx] = 0;
    if (idx < 128 * K1) {
        int nn = idx / K1, k = idx - nn * K1;
        wt1[(size_t)nn * K1 + k] = f2bf(W1[(size_t)k * 128 + nn]);
    }
    if (idx < 128 * 128) {
        int nn = idx >> 7, k = idx & 127;
        wt2[(size_t)nn * 128 + k] = f2bf(W2[(size_t)k * 128 + nn]);
    }
}

// ------------------------------- GEMM --------------------------------------
// Out[row][col] (bf16, N x 128) = A (N x K) @ W, via Wt[col][k] bf16.
// Barrier-free, LDS-free. Each wave = independent 32 rows (2x16 MFMA tiles).
// A-loads software-pipelined DEPTH=4 K-steps deep (full unroll, K constexpr);
// per iteration: B loads -> consume oldest A -> refill A slot -> MFMA (waits
// only on B; A refills stay in flight).
template <bool A_BF16, int K>
__global__ __launch_bounds__(256)
void gemm_kernel(const void* __restrict__ Aptr, const unsigned short* __restrict__ Wt,
                 unsigned short* __restrict__ Out, int nrows) {
    constexpr int NIT = K / 32;
    constexpr int DEPTH = (NIT < 4) ? NIT : 4;
    const int tid  = threadIdx.x;
    const int wave = tid >> 6;
    const int lane = tid & 63;
    const int q = lane >> 4;
    const int r = lane & 15;
    const int wrow = blockIdx.x * 128 + wave * 32;
    const size_t row0 = (size_t)min(wrow + r,      nrows - 1);
    const size_t row1 = (size_t)min(wrow + 16 + r, nrows - 1);

    const unsigned short* A16 = (const unsigned short*)Aptr;
    const float*          A32 = (const float*)Aptr;

    f32x4 acc[2][8];
#pragma unroll
    for (int s = 0; s < 2; ++s)
#pragma unroll
        for (int c = 0; c < 8; ++c) acc[s][c] = (f32x4){0.f, 0.f, 0.f, 0.f};

    bf16x8 preb[DEPTH][2];
    float4 pref[DEPTH][2][2];

    // prologue: fill the A pipe
#pragma unroll
    for (int i = 0; i < DEPTH; ++i) {
        const int kk = i * 32 + q * 8;
        if (A_BF16) {
            preb[i][0] = *reinterpret_cast<const bf16x8*>(A16 + row0 * K + kk);
            preb[i][1] = *reinterpret_cast<const bf16x8*>(A16 + row1 * K + kk);
        } else {
            pref[i][0][0] = *reinterpret_cast<const float4*>(A32 + row0 * K + kk);
            pref[i][0][1] = *reinterpret_cast<const float4*>(A32 + row0 * K + kk + 4);
            pref[i][1][0] = *reinterpret_cast<const float4*>(A32 + row1 * K + kk);
            pref[i][1][1] = *reinterpret_cast<const float4*>(A32 + row1 * K + kk + 4);
        }
    }

#pragma unroll
    for (int it = 0; it < NIT; ++it) {
        const int slot = it % DEPTH;
        const int kk = it * 32 + q * 8;

        // B fragments for this K-step (L1/L2-resident after first blocks)
        bf16x8 bfr[8];
#pragma unroll
        for (int c = 0; c < 8; ++c)
            bfr[c] = *reinterpret_cast<const bf16x8*>(Wt + (size_t)(c * 16 + r) * K + kk);

        // consume oldest A slot into afrag (waitcnt covers only these loads)
        bf16x8 afrag[2];
#pragma unroll
        for (int s = 0; s < 2; ++s) {
            if (A_BF16) {
                afrag[s] = preb[slot][s];
            } else {
                const float4 x0 = pref[slot][s][0];
                const float4 x1 = pref[slot][s][1];
                bf16x8 a;
                a[0] = (__bf16)x0.x; a[1] = (__bf16)x0.y; a[2] = (__bf16)x0.z; a[3] = (__bf16)x0.w;
                a[4] = (__bf16)x1.x; a[5] = (__bf16)x1.y; a[6] = (__bf16)x1.z; a[7] = (__bf16)x1.w;
                afrag[s] = a;
            }
        }

        // refill the pipe slot (issued after B, so MFMA's B-wait skips these)
        if (it + DEPTH < NIT) {
            const int kk2 = (it + DEPTH) * 32 + q * 8;
            if (A_BF16) {
                preb[slot][0] = *reinterpret_cast<const bf16x8*>(A16 + row0 * K + kk2);
                preb[slot][1] = *reinterpret_cast<const bf16x8*>(A16 + row1 * K + kk2);
            } else {
                pref[slot][0][0] = *reinterpret_cast<const float4*>(A32 + row0 * K + kk2);
                pref[slot][0][1] = *reinterpret_cast<const float4*>(A32 + row0 * K + kk2 + 4);
                pref[slot][1][0] = *reinterpret_cast<const float4*>(A32 + row1 * K + kk2);
                pref[slot][1][1] = *reinterpret_cast<const float4*>(A32 + row1 * K + kk2 + 4);
            }
        }

#pragma unroll
        for (int c = 0; c < 8; ++c) {
            acc[0][c] = __builtin_amdgcn_mfma_f32_16x16x32_bf16(afrag[0], bfr[c], acc[0][c], 0, 0, 0);
            acc[1][c] = __builtin_amdgcn_mfma_f32_16x16x32_bf16(afrag[1], bfr[c], acc[1][c], 0, 0, 0);
        }
    }

#pragma unroll
    for (int s = 0; s < 2; ++s)
#pragma unroll
        for (int v = 0; v < 4; ++v) {
            const int row = wrow + s * 16 + q * 4 + v;
            if (row < nrows) {
#pragma unroll
                for (int c = 0; c < 8; ++c)
                    Out[(size_t)row * 128 + c * 16 + r] = f2bf(acc[s][c][v]);
            }
        }
}

// --------------------------- Aggregation -----------------------------------
// R10: one node per 16-lane QUARTER (4 nodes/wave, 16 nodes/block). Lane
// c=lane&15 owns features 8c..8c+7 (one uint4 = 16B of the 256B row). Per
// 16-edge chunk: issue ALL 16 gathers per lane (depth-16 pipeline, pf[16]),
// prefetch next chunk's colv word, then consume into f32x2 accumulators
// (v_pk_fma). Quarter-local shfl_xor(1,2,4,8) reduction for the 2-wide
// logits; no cross-quarter merges, no duplicated epilogue.
// Tail lanes (j >= valid count) carry cw=0 -> row 0 gathered with weight 0:
// branchless and harmless (guards only at 4-edge group granularity).

#define AGG_ISSUE(g, TBL)                                                     \
    if ((g) * 4 < cnt) {                                                      \
        _Pragma("unroll")                                                     \
        for (int j = 0; j < 4; ++j) {                                         \
            const int sl = (g) * 4 + j;                                       \
            const unsigned cg = (unsigned)__shfl((int)cw, qb + sl);           \
            wt[sl] = (float)(cg & 0x7fffu) * (1.0f / 32767.0f);               \
            pf[sl] = *reinterpret_cast<const uint4*>(                         \
                (const char*)(TBL) + (((cg >> 15) << 8) + coff));             \
        }                                                                     \
    }

#define AGG_CONS(g)                                                          \
    if ((g) * 4 < cnt) {                                                     \
        _Pragma("unroll")                                                    \
        for (int j = 0; j < 4; ++j) {                                        \
            const int sl = (g) * 4 + j;                                      \
            const float w = wt[sl];                                          \
            const uint4 uu = pf[sl];                                         \
            A0 += (f32x2){bflo(uu.x), bfhi(uu.x)} * w;                       \
            A1 += (f32x2){bflo(uu.y), bfhi(uu.y)} * w;                       \
            A2 += (f32x2){bflo(uu.z), bfhi(uu.z)} * w;                       \
            A3 += (f32x2){bflo(uu.w), bfhi(uu.w)} * w;                       \
        }                                                                    \
    }

#define AGG_EDGE_LOOP(TBL)                                                   \
    unsigned cw = (beg + c < end) ? colv1[beg + c] : 0u;                     \
    for (int base = beg; base < end; base += 16) {                           \
        const int cnt = end - base;                                          \
        AGG_ISSUE(0, TBL) AGG_ISSUE(1, TBL) AGG_ISSUE(2, TBL) AGG_ISSUE(3, TBL) \
        unsigned cw_next = 0u;                                               \
        if (base + 16 + c < end) cw_next = colv1[base + 16 + c];             \
        AGG_CONS(0) AGG_CONS(1) AGG_CONS(2) AGG_CONS(3)                      \
        cw = cw_next;                                                        \
    }

__global__ __launch_bounds__(256)
void agg1_kernel(const unsigned short* __restrict__ xw, const unsigned* __restrict__ colv1,
                 const int* __restrict__ rowp, const float* __restrict__ dinv,
                 const float* __restrict__ b1, const float* __restrict__ Wc,
                 const float* __restrict__ bc, uint4* __restrict__ h1,
                 float* __restrict__ outp, int n) {
    const int node = blockIdx.x * 16 + (threadIdx.x >> 4);
    if (node >= n) return;
    const int lane = threadIdx.x & 63;
    const int c    = lane & 15;
    const int qb   = lane & 48;               // quarter base lane
    const unsigned coff = (unsigned)c << 4;
    const float di = dinv[node];
    const int beg = rowp[node], end = rowp[node + 1];

    // self-loop row: issued now, consumed after the edge loop
    const uint4 su = *reinterpret_cast<const uint4*>(
        (const char*)xw + (((unsigned)node << 8) + coff));

    f32x2 A0 = {0.f,0.f}, A1 = {0.f,0.f}, A2 = {0.f,0.f}, A3 = {0.f,0.f};
    uint4 pf[16];
    float wt[16];

    AGG_EDGE_LOOP(xw)

    A0 += (f32x2){bflo(su.x), bfhi(su.x)} * di;
    A1 += (f32x2){bflo(su.y), bfhi(su.y)} * di;
    A2 += (f32x2){bflo(su.z), bfhi(su.z)} * di;
    A3 += (f32x2){bflo(su.w), bfhi(su.w)} * di;

    const float4 bb0 = reinterpret_cast<const float4*>(b1)[2*c];
    const float4 bb1 = reinterpret_cast<const float4*>(b1)[2*c + 1];
    float a0 = fmaxf(A0[0]*di + bb0.x, 0.f), a1 = fmaxf(A0[1]*di + bb0.y, 0.f);
    float a2 = fmaxf(A1[0]*di + bb0.z, 0.f), a3 = fmaxf(A1[1]*di + bb0.w, 0.f);
    float a4 = fmaxf(A2[0]*di + bb1.x, 0.f), a5 = fmaxf(A2[1]*di + bb1.y, 0.f);
    float a6 = fmaxf(A3[0]*di + bb1.z, 0.f), a7 = fmaxf(A3[1]*di + bb1.w, 0.f);

    h1[((unsigned)node << 4) + c] =
        make_uint4(packbf(a0,a1), packbf(a2,a3), packbf(a4,a5), packbf(a6,a7));

    const float4 w0 = reinterpret_cast<const float4*>(Wc)[4*c];
    const float4 w1 = reinterpret_cast<const float4*>(Wc)[4*c + 1];
    const float4 w2 = reinterpret_cast<const float4*>(Wc)[4*c + 2];
    const float4 w3 = reinterpret_cast<const float4*>(Wc)[4*c + 3];
    float c0 = a0*w0.x + a1*w0.z + a2*w1.x + a3*w1.z
             + a4*w2.x + a5*w2.z + a6*w3.x + a7*w3.z;
    float c1 = a0*w0.y + a1*w0.w + a2*w1.y + a3*w1.w
             + a4*w2.y + a5*w2.w + a6*w3.y + a7*w3.w;
#pragma unroll
    for (int off = 1; off < 16; off <<= 1) {       // quarter-local reduce
        c0 += __shfl_xor(c0, off);
        c1 += __shfl_xor(c1, off);
    }
    if (c == 0) {
        outp[2 * (size_t)node]     = 0.5f * (c0 + bc[0]);
        outp[2 * (size_t)node + 1] = 0.5f * (c1 + bc[1]);
    }
}

__global__ __launch_bounds__(256)
void agg2_kernel(const unsigned short* __restrict__ xw2, const uint4* __restrict__ h1,
                 const unsigned* __restrict__ colv1, const int* __restrict__ rowp,
                 const float* __restrict__ dinv, const float* __restrict__ b2,
                 const float* __restrict__ Wf, const float* __restrict__ bfv,
                 const float* __restrict__ hnode, float* __restrict__ outp, int n) {
    const int node = blockIdx.x * 16 + (threadIdx.x >> 4);
    if (node >= n) return;
    const int lane = threadIdx.x & 63;
    const int c    = lane & 15;
    const int qb   = lane & 48;
    const unsigned coff = (unsigned)c << 4;
    const float di = dinv[node];
    const int beg = rowp[node], end = rowp[node + 1];

    const uint4 su = *reinterpret_cast<const uint4*>(
        (const char*)xw2 + (((unsigned)node << 8) + coff));

    f32x2 A0 = {0.f,0.f}, A1 = {0.f,0.f}, A2 = {0.f,0.f}, A3 = {0.f,0.f};
    uint4 pf[16];
    float wt[16];

    AGG_EDGE_LOOP(xw2)

    A0 += (f32x2){bflo(su.x), bfhi(su.x)} * di;
    A1 += (f32x2){bflo(su.y), bfhi(su.y)} * di;
    A2 += (f32x2){bflo(su.z), bfhi(su.z)} * di;
    A3 += (f32x2){bflo(su.w), bfhi(su.w)} * di;

    const float4 bb0 = reinterpret_cast<const float4*>(b2)[2*c];
    const float4 bb1 = reinterpret_cast<const float4*>(b2)[2*c + 1];
    float h20 = fmaxf(A0[0]*di + bb0.x, 0.f), h21 = fmaxf(A0[1]*di + bb0.y, 0.f);
    float h22 = fmaxf(A1[0]*di + bb0.z, 0.f), h23 = fmaxf(A1[1]*di + bb0.w, 0.f);
    float h24 = fmaxf(A2[0]*di + bb1.x, 0.f), h25 = fmaxf(A2[1]*di + bb1.y, 0.f);
    float h26 = fmaxf(A3[0]*di + bb1.z, 0.f), h27 = fmaxf(A3[1]*di + bb1.w, 0.f);

    const float alpha = hnode[node];
    const float beta  = 1.f - alpha;
    const uint4 hh = h1[((unsigned)node << 4) + c];
    const float ha0 = alpha*h20 + beta*bflo(hh.x);
    const float ha1 = alpha*h21 + beta*bfhi(hh.x);
    const float ha2 = alpha*h22 + beta*bflo(hh.y);
    const float ha3 = alpha*h23 + beta*bfhi(hh.y);
    const float ha4 = alpha*h24 + beta*bflo(hh.z);
    const float ha5 = alpha*h25 + beta*bfhi(hh.z);
    const float ha6 = alpha*h26 + beta*bflo(hh.w);
    const float ha7 = alpha*h27 + beta*bfhi(hh.w);

    const float4 w0 = reinterpret_cast<const float4*>(Wf)[4*c];
    const float4 w1 = reinterpret_cast<const float4*>(Wf)[4*c + 1];
    const float4 w2 = reinterpret_cast<const float4*>(Wf)[4*c + 2];
    const float4 w3 = reinterpret_cast<const float4*>(Wf)[4*c + 3];
    float f0 = ha0*w0.x + ha1*w0.z + ha2*w1.x + ha3*w1.z
             + ha4*w2.x + ha5*w2.z + ha6*w3.x + ha7*w3.z;
    float f1 = ha0*w0.y + ha1*w0.w + ha2*w1.y + ha3*w1.w
             + ha4*w2.y + ha5*w2.w + ha6*w3.y + ha7*w3.w;
#pragma unroll
    for (int off = 1; off < 16; off <<= 1) {
        f0 += __shfl_xor(f0, off);
        f1 += __shfl_xor(f1, off);
    }
    if (c == 0) {
        outp[2 * (size_t)node]     += 0.5f * (f0 + bfv[0]);
        outp[2 * (size_t)node + 1] += 0.5f * (f1 + bfv[1]);
    }
}

// ------------------------------ launch -------------------------------------

extern "C" void kernel_launch(void* const* d_in, const int* in_sizes, int n_in,
                              void* d_out, int out_size, void* d_ws, size_t ws_size,
                              hipStream_t stream) {
    const float* x     = (const float*)d_in[0];
    const int*   ei    = (const int*)d_in[1];     // int32 per harness contract
    const float* hnode = (const float*)d_in[2];
    const float* W1    = (const float*)d_in[3];
    const float* b1    = (const float*)d_in[4];
    const float* W2    = (const float*)d_in[5];
    const float* b2    = (const float*)d_in[6];
    const float* Wc    = (const float*)d_in[7];
    const float* bc    = (const float*)d_in[8];
    const float* Wf    = (const float*)d_in[9];
    const float* bfv   = (const float*)d_in[10];

    const int N  = in_sizes[2];
    const int E  = in_sizes[1] / 2;
    const int K1 = in_sizes[3] / HID;   // 256 (fixed by problem shape)
    const int NB = (N + RANGE - 1) >> SHIFT;
    const int* srcv = ei;
    const int* dstv = ei + E;
    float* outp = (float*)d_out;

    char* ws = (char*)d_ws;
    size_t off = 0;
    auto alloc = [&](size_t bytes) -> char* {
        char* p = ws + off;
        off += (bytes + 255) & ~(size_t)255;
        return p;
    };
    unsigned short* xw       = (unsigned short*)alloc((size_t)N * HID * 2);  // 25.6 MB
    unsigned short* h1       = (unsigned short*)alloc((size_t)N * HID * 2);  // 25.6 MB
    float*          dinv     = (float*)alloc((size_t)N * 4);
    int*            rowp     = (int*)alloc((size_t)(N + 1) * 4);
    unsigned*       colv1    = (unsigned*)alloc((size_t)E * 4);              // 6.4 MB
    unsigned*       pairs    = (unsigned*)alloc((size_t)E * 4);              // 6.4 MB
    int*            bin_counts = (int*)alloc(MAXB * 4);
    int*            bin_off    = (int*)alloc(MAXB * 4);
    int*            bin_cur    = (int*)alloc(MAXB * 4);
    unsigned short* wt1      = (unsigned short*)alloc((size_t)HID * K1 * 2);
    unsigned short* wt2      = (unsigned short*)alloc((size_t)HID * HID * 2);

    prep_kernel<<<(HID * K1 + 255) / 256, 256, 0, stream>>>(W1, W2, wt1, wt2, K1, bin_counts);

    const int ntiles = (E + TILE - 1) / TILE;
    bincount_kernel<<<ntiles, 256, 0, stream>>>(dstv, bin_counts, E, NB);
    binscan_kernel<<<1, 256, 0, stream>>>(bin_counts, bin_off, bin_cur, NB);
    stage_kernel<<<ntiles, 256, 0, stream>>>(srcv, dstv, bin_cur, pairs, E);
    binrowp_kernel<<<NB, 256, 0, stream>>>(pairs, bin_off, dinv, rowp, N, NB, E);
    fine_kernel<<<NB, 256, 0, stream>>>(pairs, bin_off, rowp, dinv, colv1, N, NB, E);

    gemm_kernel<false, 256><<<(N + 127) / 128, 256, 0, stream>>>((const void*)x, wt1, xw, N);
    agg1_kernel<<<(N + 15) / 16, 256, 0, stream>>>(xw, colv1, rowp, dinv,
                                                   b1, Wc, bc, (uint4*)h1, outp, N);
    gemm_kernel<true, 128><<<(N + 127) / 128, 256, 0, stream>>>((const void*)h1, wt2, xw, N);
    agg2_kernel<<<(N + 15) / 16, 256, 0, stream>>>(xw, (const uint4*)h1, colv1,
                                                   rowp, dinv, b2, Wf, bfv, hnode, outp, N);
}

// Round 2
// 388.565 us; speedup vs baseline: 1.1132x; 1.0362x over previous
//
#include <hip/hip_runtime.h>

// ---------------------------------------------------------------------------
// GCN 2-layer fused pipeline for MI355X (gfx950)
//   h1 = relu(Dinv (A+I) Dinv (x@W1) + b1)
//   out = 0.5*(h1@Wc + bc) + 0.5*((alpha*h2 + (1-alpha)*h1)@Wf + bf)
//   h2 = relu(Dinv (A+I) Dinv (h1@W2) + b2)
// R2: binned counting-sort CSR. R3: fused dinv into colv. R5/R6: multi-edge
// wide gathers. R8: 1-dword colv (st<<15|w15), packed f32x2 agg math.
// R9: barrier-free register-pipelined GEMM (no LDS, no syncthreads).
// R10: agg one-node-per-QUARTER, depth-16 gather pipe (+30us total).
// R11: gemm B moved to LDS. Diagnosis: per-iteration global B-loads forced
// vmcnt drain of the whole A pipe every 16 MFMAs (MfmaUtil 3.5%, HBM 1.15
// TB/s = latency-paced). Now Wt staged to LDS once (XOR-swizzled chunks:
// kc ^ (col & (CH-1)) -> ~2-way banks on the 16-col-stride ds_read_b128),
// B double-buffered in regs on lgkmcnt, K-loop barrier-free; vmcnt covers
// ONLY the A pipe (DEPTH=4 slots stay in flight -> HBM-paced streaming).
// ---------------------------------------------------------------------------

#define HID 128
#define SHIFT 9
#define RANGE 512           // nodes per bin = 1<<SHIFT
#define MAXB 256            // max bins (N <= 131072)
#define TILE 4096           // edges per stage block

typedef __bf16 bf16x8 __attribute__((ext_vector_type(8)));
typedef float  f32x4  __attribute__((ext_vector_type(4)));
typedef float  f32x2  __attribute__((ext_vector_type(2)));

__device__ __forceinline__ unsigned short f2bf(float x) {
    unsigned int b = __float_as_uint(x);
    b += 0x7fffu + ((b >> 16) & 1u);     // round-to-nearest-even
    return (unsigned short)(b >> 16);
}
__device__ __forceinline__ float bflo(unsigned int u) { return __uint_as_float(u << 16); }
__device__ __forceinline__ float bfhi(unsigned int u) { return __uint_as_float(u & 0xffff0000u); }
__device__ __forceinline__ unsigned packbf(float a, float b) {
    return (unsigned)f2bf(a) | ((unsigned)f2bf(b) << 16);
}

// --------------------------- binned CSR build ------------------------------

__global__ __launch_bounds__(256)
void bincount_kernel(const int* __restrict__ dst, int* __restrict__ bin_counts,
                     int E, int NB) {
    __shared__ int h[MAXB];
    for (int i = threadIdx.x; i < NB; i += 256) h[i] = 0;
    __syncthreads();
    const int base = blockIdx.x * TILE;
#pragma unroll
    for (int j = 0; j < TILE; j += 256) {
        int e = base + j + threadIdx.x;
        if (e < E) atomicAdd(&h[((unsigned)dst[e]) >> SHIFT], 1);
    }
    __syncthreads();
    for (int i = threadIdx.x; i < NB; i += 256) {
        int v = h[i];
        if (v) atomicAdd(&bin_counts[i], v);
    }
}

__global__ void binscan_kernel(const int* __restrict__ bin_counts,
                               int* __restrict__ bin_off, int* __restrict__ bin_cur, int NB) {
    __shared__ int sh[MAXB];
    const int t = threadIdx.x;
    int v = (t < NB) ? bin_counts[t] : 0;
    sh[t] = v;
    __syncthreads();
    for (int s = 1; s < 256; s <<= 1) {
        int x = (t >= s) ? sh[t - s] : 0;
        __syncthreads();
        sh[t] += x;
        __syncthreads();
    }
    if (t < NB) {
        int ex = sh[t] - v;     // exclusive
        bin_off[t] = ex;
        bin_cur[t] = ex;
    }
}

// Block-level binning: tile-local LDS sort by bin, then bin-sorted write-out
// in contiguous runs. pairs[i] = (dlocal<<23) | src   (src < 2^23).
__global__ __launch_bounds__(256)
void stage_kernel(const int* __restrict__ src, const int* __restrict__ dst,
                  int* __restrict__ bin_cur, unsigned* __restrict__ pairs, int E) {
    __shared__ int sh_hist[MAXB];
    __shared__ int sh_off[MAXB];
    __shared__ int sh_ex[MAXB];
    __shared__ int sh_gbase[MAXB];
    __shared__ uint2 stg[TILE];
    const int t = threadIdx.x;
    const int base = blockIdx.x * TILE;
    const int cnt = min(TILE, E - base);

    for (int i = t; i < MAXB; i += 256) sh_hist[i] = 0;
    __syncthreads();

    int s[16], d[16], r[16];
#pragma unroll
    for (int j = 0; j < 16; ++j) {
        const int k = j * 256 + t;
        if (k < cnt) {
            s[j] = src[base + k];
            d[j] = dst[base + k];
            r[j] = atomicAdd(&sh_hist[((unsigned)d[j]) >> SHIFT], 1);
        }
    }
    __syncthreads();

    const int hv = sh_hist[t];
    sh_off[t] = hv;
    __syncthreads();
    for (int st = 1; st < 256; st <<= 1) {
        int x = (t >= st) ? sh_off[t - st] : 0;
        __syncthreads();
        sh_off[t] += x;
        __syncthreads();
    }
    sh_ex[t] = sh_off[t] - hv;                      // exclusive within tile
    if (hv > 0) sh_gbase[t] = atomicAdd(&bin_cur[t], hv);
    __syncthreads();

#pragma unroll
    for (int j = 0; j < 16; ++j) {
        const int k = j * 256 + t;
        if (k < cnt) {
            int b = ((unsigned)d[j]) >> SHIFT;
            stg[sh_ex[b] + r[j]] = make_uint2((unsigned)s[j], (unsigned)d[j]);
        }
    }
    __syncthreads();

    for (int i = t; i < cnt; i += 256) {
        uint2 p = stg[i];
        int b = (int)(p.y >> SHIFT);
        unsigned w = ((p.y & (RANGE - 1)) << 23) | p.x;
        pairs[sh_gbase[b] + (i - sh_ex[b])] = w;
    }
}

// Per-bin: histogram pairs -> counts; intra-bin scan (+bin_off base) -> rowp;
// dinv from counts.
__global__ __launch_bounds__(256)
void binrowp_kernel(const unsigned* __restrict__ pairs, const int* __restrict__ bin_off,
                    float* __restrict__ dinv, int* __restrict__ rowp,
                    int N, int NB, int E) {
    __shared__ int c[RANGE];
    __shared__ int sh[256];
    const int b = blockIdx.x;
    const int t = threadIdx.x;
    const int nb = b << SHIFT;
    const int nr = min(RANGE, N - nb);
    for (int i = t; i < RANGE; i += 256) c[i] = 0;
    __syncthreads();
    const int lo = bin_off[b];
    const int hi = (b + 1 < NB) ? bin_off[b + 1] : E;
    for (int i = lo + t; i < hi; i += 256)
        atomicAdd(&c[pairs[i] >> 23], 1);
    __syncthreads();
    const int v0 = c[2 * t], v1 = c[2 * t + 1];
    const int pr = v0 + v1;
    sh[t] = pr;
    __syncthreads();
    for (int s = 1; s < 256; s <<= 1) {
        int x = (t >= s) ? sh[t - s] : 0;
        __syncthreads();
        sh[t] += x;
        __syncthreads();
    }
    const int ex = sh[t] - pr + lo;     // exclusive prefix + bin edge base
    if (2 * t < nr) {
        rowp[nb + 2 * t] = ex;
        dinv[nb + 2 * t] = rsqrtf((float)(v0 + 1));
    }
    if (2 * t + 1 < nr) {
        rowp[nb + 2 * t + 1] = ex + v0;
        dinv[nb + 2 * t + 1] = rsqrtf((float)(v1 + 1));
    }
    if (b == 0 && t == 0) rowp[N] = E;
}

// Per-bin fine scatter; emits packed (src<<15)|fixed15(dinv[src])
__global__ __launch_bounds__(256)
void fine_kernel(const unsigned* __restrict__ pairs, const int* __restrict__ bin_off,
                 const int* __restrict__ rowp, const float* __restrict__ dinv,
                 unsigned* __restrict__ colv1, int N, int NB, int E) {
    __shared__ int cur[RANGE];
    const int b = blockIdx.x;
    const int nb = b << SHIFT;
    const int nr = min(RANGE, N - nb);
    for (int i = threadIdx.x; i < nr; i += 256) cur[i] = rowp[nb + i];
    __syncthreads();
    const int lo = bin_off[b];
    const int hi = (b + 1 < NB) ? bin_off[b + 1] : E;
    for (int i = lo + threadIdx.x; i < hi; i += 256) {
        unsigned w = pairs[i];
        unsigned s = w & 0x7fffffu;
        int pos = atomicAdd(&cur[w >> 23], 1);
        unsigned w15 = __float2uint_rn(dinv[s] * 32767.0f);   // dinv in (0,1]
        colv1[pos] = (s << 15) | w15;
    }
}

// Merged prep: zero bin_counts + both weight transposes (Wt[col][k] bf16)
__global__ void prep_kernel(const float* __restrict__ W1, const float* __restrict__ W2,
                            unsigned short* __restrict__ wt1, unsigned short* __restrict__ wt2,
                            int K1, int* __restrict__ bin_counts) {
    int idx = blockIdx.x * 256 + threadIdx.x;
    if (idx < MAXB) bin_counts[idx] = 0;
    if (idx < 128 * K1) {
        int nn = idx / K1, k = idx - nn * K1;
        wt1[(size_t)nn * K1 + k] = f2bf(W1[(size_t)k * 128 + nn]);
    }
    if (idx < 128 * 128) {
        int nn = idx >> 7, k = idx & 127;
        wt2[(size_t)nn * 128 + k] = f2bf(W2[(size_t)k * 128 + nn]);
    }
}

// ------------------------------- GEMM --------------------------------------
// Out[row][col] (bf16, N x 128) = A (N x K) @ W, via Wt[col][k] bf16.
// R11 structure: Wt staged into LDS once (swizzled), then a barrier-free
// K-loop. Each wave = independent 32 rows (2x16 MFMA tiles). A-loads run a
// DEPTH=4 register pipe whose vmcnt waits cover ONLY A (12KB/wave stays in
// flight). B fragments ds_read_b128 from LDS, double-buffered one iteration
// ahead (lgkmcnt hidden under MFMA). Swizzle: 16B-chunk index kc stored at
// kc ^ (col & (CH-1)); read with same XOR -> banks spread ~2-way (free).
template <bool A_BF16, int K>
__global__ __launch_bounds__(256)
void gemm_kernel(const void* __restrict__ Aptr, const unsigned short* __restrict__ Wt,
                 unsigned short* __restrict__ Out, int nrows) {
    constexpr int NIT = K / 32;
    constexpr int DEPTH = (NIT < 4) ? NIT : 4;
    constexpr int CH = K / 8;              // 16B chunks per B row
    __shared__ uint4 sB[128 * CH];         // 64KB (K=256) / 32KB (K=128)

    const int tid  = threadIdx.x;
    const int wave = tid >> 6;
    const int lane = tid & 63;
    const int q = lane >> 4;
    const int r = lane & 15;

    // ---- stage B into LDS (once), swizzled; coalesced global reads ----
    for (int idx = tid; idx < 128 * CH; idx += 256) {
        const int col = idx / CH;
        const int kc  = idx & (CH - 1);
        const uint4 v = *reinterpret_cast<const uint4*>(Wt + (size_t)col * K + kc * 8);
        sB[col * CH + (kc ^ (col & (CH - 1)))] = v;
    }
    __syncthreads();

    const int wrow = blockIdx.x * 128 + wave * 32;
    const size_t row0 = (size_t)min(wrow + r,      nrows - 1);
    const size_t row1 = (size_t)min(wrow + 16 + r, nrows - 1);

    const unsigned short* A16 = (const unsigned short*)Aptr;
    const float*          A32 = (const float*)Aptr;

    f32x4 acc[2][8];
#pragma unroll
    for (int s = 0; s < 2; ++s)
#pragma unroll
        for (int c = 0; c < 8; ++c) acc[s][c] = (f32x4){0.f, 0.f, 0.f, 0.f};

    bf16x8 preb[DEPTH][2];
    float4 pref[DEPTH][2][2];

    // prologue: fill the A pipe
#pragma unroll
    for (int i = 0; i < DEPTH; ++i) {
        const int kk = i * 32 + q * 8;
        if (A_BF16) {
            preb[i][0] = *reinterpret_cast<const bf16x8*>(A16 + row0 * K + kk);
            preb[i][1] = *reinterpret_cast<const bf16x8*>(A16 + row1 * K + kk);
        } else {
            pref[i][0][0] = *reinterpret_cast<const float4*>(A32 + row0 * K + kk);
            pref[i][0][1] = *reinterpret_cast<const float4*>(A32 + row0 * K + kk + 4);
            pref[i][1][0] = *reinterpret_cast<const float4*>(A32 + row1 * K + kk);
            pref[i][1][1] = *reinterpret_cast<const float4*>(A32 + row1 * K + kk + 4);
        }
    }

    // B fragment loader from swizzled LDS: chunk index for iter it_ is it_*4+q
    auto ldB = [&](int it_, int c_) -> bf16x8 {
        const int col = c_ * 16 + r;
        const int chunk = (it_ * 4 + q) ^ (col & (CH - 1));
        return *reinterpret_cast<const bf16x8*>(&sB[col * CH + chunk]);
    };

    bf16x8 bcur[8], bnxt[8];
#pragma unroll
    for (int c = 0; c < 8; ++c) bcur[c] = ldB(0, c);

#pragma unroll
    for (int it = 0; it < NIT; ++it) {
        const int slot = it % DEPTH;

        // prefetch next iteration's B from LDS (lgkmcnt, hidden under MFMA)
        if (it + 1 < NIT) {
#pragma unroll
            for (int c = 0; c < 8; ++c) bnxt[c] = ldB(it + 1, c);
        }

        // consume oldest A slot into afrag (vmcnt waits only on A pipe)
        bf16x8 afrag[2];
#pragma unroll
        for (int s = 0; s < 2; ++s) {
            if (A_BF16) {
                afrag[s] = preb[slot][s];
            } else {
                const float4 x0 = pref[slot][s][0];
                const float4 x1 = pref[slot][s][1];
                bf16x8 a;
                a[0] = (__bf16)x0.x; a[1] = (__bf16)x0.y; a[2] = (__bf16)x0.z; a[3] = (__bf16)x0.w;
                a[4] = (__bf16)x1.x; a[5] = (__bf16)x1.y; a[6] = (__bf16)x1.z; a[7] = (__bf16)x1.w;
                afrag[s] = a;
            }
        }

        // refill the pipe slot (stays in flight across following iterations)
        if (it + DEPTH < NIT) {
            const int kk2 = (it + DEPTH) * 32 + q * 8;
            if (A_BF16) {
                preb[slot][0] = *reinterpret_cast<const bf16x8*>(A16 + row0 * K + kk2);
                preb[slot][1] = *reinterpret_cast<const bf16x8*>(A16 + row1 * K + kk2);
            } else {
                pref[slot][0][0] = *reinterpret_cast<const float4*>(A32 + row0 * K + kk2);
                pref[slot][0][1] = *reinterpret_cast<const float4*>(A32 + row0 * K + kk2 + 4);
                pref[slot][1][0] = *reinterpret_cast<const float4*>(A32 + row1 * K + kk2);
                pref[slot][1][1] = *reinterpret_cast<const float4*>(A32 + row1 * K + kk2 + 4);
            }
        }

#pragma unroll
        for (int c = 0; c < 8; ++c) {
            acc[0][c] = __builtin_amdgcn_mfma_f32_16x16x32_bf16(afrag[0], bcur[c], acc[0][c], 0, 0, 0);
            acc[1][c] = __builtin_amdgcn_mfma_f32_16x16x32_bf16(afrag[1], bcur[c], acc[1][c], 0, 0, 0);
        }

        if (it + 1 < NIT) {
#pragma unroll
            for (int c = 0; c < 8; ++c) bcur[c] = bnxt[c];
        }
    }

#pragma unroll
    for (int s = 0; s < 2; ++s)
#pragma unroll
        for (int v = 0; v < 4; ++v) {
            const int row = wrow + s * 16 + q * 4 + v;
            if (row < nrows) {
#pragma unroll
                for (int c = 0; c < 8; ++c)
                    Out[(size_t)row * 128 + c * 16 + r] = f2bf(acc[s][c][v]);
            }
        }
}

// --------------------------- Aggregation -----------------------------------
// R10: one node per 16-lane QUARTER (4 nodes/wave, 16 nodes/block). Lane
// c=lane&15 owns features 8c..8c+7 (one uint4 = 16B of the 256B row). Per
// 16-edge chunk: issue ALL 16 gathers per lane (depth-16 pipeline, pf[16]),
// prefetch next chunk's colv word, then consume into f32x2 accumulators
// (v_pk_fma). Quarter-local shfl_xor(1,2,4,8) reduction for the 2-wide
// logits; no cross-quarter merges, no duplicated epilogue.
// Tail lanes (j >= valid count) carry cw=0 -> row 0 gathered with weight 0:
// branchless and harmless (guards only at 4-edge group granularity).

#define AGG_ISSUE(g, TBL)                                                     \
    if ((g) * 4 < cnt) {                                                      \
        _Pragma("unroll")                                                     \
        for (int j = 0; j < 4; ++j) {                                         \
            const int sl = (g) * 4 + j;                                       \
            const unsigned cg = (unsigned)__shfl((int)cw, qb + sl);           \
            wt[sl] = (float)(cg & 0x7fffu) * (1.0f / 32767.0f);               \
            pf[sl] = *reinterpret_cast<const uint4*>(                         \
                (const char*)(TBL) + (((cg >> 15) << 8) + coff));             \
        }                                                                     \
    }

#define AGG_CONS(g)                                                          \
    if ((g) * 4 < cnt) {                                                     \
        _Pragma("unroll")                                                    \
        for (int j = 0; j < 4; ++j) {                                        \
            const int sl = (g) * 4 + j;                                      \
            const float w = wt[sl];                                          \
            const uint4 uu = pf[sl];                                         \
            A0 += (f32x2){bflo(uu.x), bfhi(uu.x)} * w;                       \
            A1 += (f32x2){bflo(uu.y), bfhi(uu.y)} * w;                       \
            A2 += (f32x2){bflo(uu.z), bfhi(uu.z)} * w;                       \
            A3 += (f32x2){bflo(uu.w), bfhi(uu.w)} * w;                       \
        }                                                                    \
    }

#define AGG_EDGE_LOOP(TBL)                                                   \
    unsigned cw = (beg + c < end) ? colv1[beg + c] : 0u;                     \
    for (int base = beg; base < end; base += 16) {                           \
        const int cnt = end - base;                                          \
        AGG_ISSUE(0, TBL) AGG_ISSUE(1, TBL) AGG_ISSUE(2, TBL) AGG_ISSUE(3, TBL) \
        unsigned cw_next = 0u;                                               \
        if (base + 16 + c < end) cw_next = colv1[base + 16 + c];             \
        AGG_CONS(0) AGG_CONS(1) AGG_CONS(2) AGG_CONS(3)                      \
        cw = cw_next;                                                        \
    }

__global__ __launch_bounds__(256)
void agg1_kernel(const unsigned short* __restrict__ xw, const unsigned* __restrict__ colv1,
                 const int* __restrict__ rowp, const float* __restrict__ dinv,
                 const float* __restrict__ b1, const float* __restrict__ Wc,
                 const float* __restrict__ bc, uint4* __restrict__ h1,
                 float* __restrict__ outp, int n) {
    const int node = blockIdx.x * 16 + (threadIdx.x >> 4);
    if (node >= n) return;
    const int lane = threadIdx.x & 63;
    const int c    = lane & 15;
    const int qb   = lane & 48;               // quarter base lane
    const unsigned coff = (unsigned)c << 4;
    const float di = dinv[node];
    const int beg = rowp[node], end = rowp[node + 1];

    // self-loop row: issued now, consumed after the edge loop
    const uint4 su = *reinterpret_cast<const uint4*>(
        (const char*)xw + (((unsigned)node << 8) + coff));

    f32x2 A0 = {0.f,0.f}, A1 = {0.f,0.f}, A2 = {0.f,0.f}, A3 = {0.f,0.f};
    uint4 pf[16];
    float wt[16];

    AGG_EDGE_LOOP(xw)

    A0 += (f32x2){bflo(su.x), bfhi(su.x)} * di;
    A1 += (f32x2){bflo(su.y), bfhi(su.y)} * di;
    A2 += (f32x2){bflo(su.z), bfhi(su.z)} * di;
    A3 += (f32x2){bflo(su.w), bfhi(su.w)} * di;

    const float4 bb0 = reinterpret_cast<const float4*>(b1)[2*c];
    const float4 bb1 = reinterpret_cast<const float4*>(b1)[2*c + 1];
    float a0 = fmaxf(A0[0]*di + bb0.x, 0.f), a1 = fmaxf(A0[1]*di + bb0.y, 0.f);
    float a2 = fmaxf(A1[0]*di + bb0.z, 0.f), a3 = fmaxf(A1[1]*di + bb0.w, 0.f);
    float a4 = fmaxf(A2[0]*di + bb1.x, 0.f), a5 = fmaxf(A2[1]*di + bb1.y, 0.f);
    float a6 = fmaxf(A3[0]*di + bb1.z, 0.f), a7 = fmaxf(A3[1]*di + bb1.w, 0.f);

    h1[((unsigned)node << 4) + c] =
        make_uint4(packbf(a0,a1), packbf(a2,a3), packbf(a4,a5), packbf(a6,a7));

    const float4 w0 = reinterpret_cast<const float4*>(Wc)[4*c];
    const float4 w1 = reinterpret_cast<const float4*>(Wc)[4*c + 1];
    const float4 w2 = reinterpret_cast<const float4*>(Wc)[4*c + 2];
    const float4 w3 = reinterpret_cast<const float4*>(Wc)[4*c + 3];
    float c0 = a0*w0.x + a1*w0.z + a2*w1.x + a3*w1.z
             + a4*w2.x + a5*w2.z + a6*w3.x + a7*w3.z;
    float c1 = a0*w0.y + a1*w0.w + a2*w1.y + a3*w1.w
             + a4*w2.y + a5*w2.w + a6*w3.y + a7*w3.w;
#pragma unroll
    for (int off = 1; off < 16; off <<= 1) {       // quarter-local reduce
        c0 += __shfl_xor(c0, off);
        c1 += __shfl_xor(c1, off);
    }
    if (c == 0) {
        outp[2 * (size_t)node]     = 0.5f * (c0 + bc[0]);
        outp[2 * (size_t)node + 1] = 0.5f * (c1 + bc[1]);
    }
}

__global__ __launch_bounds__(256)
void agg2_kernel(const unsigned short* __restrict__ xw2, const uint4* __restrict__ h1,
                 const unsigned* __restrict__ colv1, const int* __restrict__ rowp,
                 const float* __restrict__ dinv, const float* __restrict__ b2,
                 const float* __restrict__ Wf, const float* __restrict__ bfv,
                 const float* __restrict__ hnode, float* __restrict__ outp, int n) {
    const int node = blockIdx.x * 16 + (threadIdx.x >> 4);
    if (node >= n) return;
    const int lane = threadIdx.x & 63;
    const int c    = lane & 15;
    const int qb   = lane & 48;
    const unsigned coff = (unsigned)c << 4;
    const float di = dinv[node];
    const int beg = rowp[node], end = rowp[node + 1];

    const uint4 su = *reinterpret_cast<const uint4*>(
        (const char*)xw2 + (((unsigned)node << 8) + coff));

    f32x2 A0 = {0.f,0.f}, A1 = {0.f,0.f}, A2 = {0.f,0.f}, A3 = {0.f,0.f};
    uint4 pf[16];
    float wt[16];

    AGG_EDGE_LOOP(xw2)

    A0 += (f32x2){bflo(su.x), bfhi(su.x)} * di;
    A1 += (f32x2){bflo(su.y), bfhi(su.y)} * di;
    A2 += (f32x2){bflo(su.z), bfhi(su.z)} * di;
    A3 += (f32x2){bflo(su.w), bfhi(su.w)} * di;

    const float4 bb0 = reinterpret_cast<const float4*>(b2)[2*c];
    const float4 bb1 = reinterpret_cast<const float4*>(b2)[2*c + 1];
    float h20 = fmaxf(A0[0]*di + bb0.x, 0.f), h21 = fmaxf(A0[1]*di + bb0.y, 0.f);
    float h22 = fmaxf(A1[0]*di + bb0.z, 0.f), h23 = fmaxf(A1[1]*di + bb0.w, 0.f);
    float h24 = fmaxf(A2[0]*di + bb1.x, 0.f), h25 = fmaxf(A2[1]*di + bb1.y, 0.f);
    float h26 = fmaxf(A3[0]*di + bb1.z, 0.f), h27 = fmaxf(A3[1]*di + bb1.w, 0.f);

    const float alpha = hnode[node];
    const float beta  = 1.f - alpha;
    const uint4 hh = h1[((unsigned)node << 4) + c];
    const float ha0 = alpha*h20 + beta*bflo(hh.x);
    const float ha1 = alpha*h21 + beta*bfhi(hh.x);
    const float ha2 = alpha*h22 + beta*bflo(hh.y);
    const float ha3 = alpha*h23 + beta*bfhi(hh.y);
    const float ha4 = alpha*h24 + beta*bflo(hh.z);
    const float ha5 = alpha*h25 + beta*bfhi(hh.z);
    const float ha6 = alpha*h26 + beta*bflo(hh.w);
    const float ha7 = alpha*h27 + beta*bfhi(hh.w);

    const float4 w0 = reinterpret_cast<const float4*>(Wf)[4*c];
    const float4 w1 = reinterpret_cast<const float4*>(Wf)[4*c + 1];
    const float4 w2 = reinterpret_cast<const float4*>(Wf)[4*c + 2];
    const float4 w3 = reinterpret_cast<const float4*>(Wf)[4*c + 3];
    float f0 = ha0*w0.x + ha1*w0.z + ha2*w1.x + ha3*w1.z
             + ha4*w2.x + ha5*w2.z + ha6*w3.x + ha7*w3.z;
    float f1 = ha0*w0.y + ha1*w0.w + ha2*w1.y + ha3*w1.w
             + ha4*w2.y + ha5*w2.w + ha6*w3.y + ha7*w3.w;
#pragma unroll
    for (int off = 1; off < 16; off <<= 1) {
        f0 += __shfl_xor(f0, off);
        f1 += __shfl_xor(f1, off);
    }
    if (c == 0) {
        outp[2 * (size_t)node]     += 0.5f * (f0 + bfv[0]);
        outp[2 * (size_t)node + 1] += 0.5f * (f1 + bfv[1]);
    }
}

// ------------------------------ launch -------------------------------------

extern "C" void kernel_launch(void* const* d_in, const int* in_sizes, int n_in,
                              void* d_out, int out_size, void* d_ws, size_t ws_size,
                              hipStream_t stream) {
    const float* x     = (const float*)d_in[0];
    const int*   ei    = (const int*)d_in[1];     // int32 per harness contract
    const float* hnode = (const float*)d_in[2];
    const float* W1    = (const float*)d_in[3];
    const float* b1    = (const float*)d_in[4];
    const float* W2    = (const float*)d_in[5];
    const float* b2    = (const float*)d_in[6];
    const float* Wc    = (const float*)d_in[7];
    const float* bc    = (const float*)d_in[8];
    const float* Wf    = (const float*)d_in[9];
    const float* bfv   = (const float*)d_in[10];

    const int N  = in_sizes[2];
    const int E  = in_sizes[1] / 2;
    const int K1 = in_sizes[3] / HID;   // 256 (fixed by problem shape)
    const int NB = (N + RANGE - 1) >> SHIFT;
    const int* srcv = ei;
    const int* dstv = ei + E;
    float* outp = (float*)d_out;

    char* ws = (char*)d_ws;
    size_t off = 0;
    auto alloc = [&](size_t bytes) -> char* {
        char* p = ws + off;
        off += (bytes + 255) & ~(size_t)255;
        return p;
    };
    unsigned short* xw       = (unsigned short*)alloc((size_t)N * HID * 2);  // 25.6 MB
    unsigned short* h1       = (unsigned short*)alloc((size_t)N * HID * 2);  // 25.6 MB
    float*          dinv     = (float*)alloc((size_t)N * 4);
    int*            rowp     = (int*)alloc((size_t)(N + 1) * 4);
    unsigned*       colv1    = (unsigned*)alloc((size_t)E * 4);              // 6.4 MB
    unsigned*       pairs    = (unsigned*)alloc((size_t)E * 4);              // 6.4 MB
    int*            bin_counts = (int*)alloc(MAXB * 4);
    int*            bin_off    = (int*)alloc(MAXB * 4);
    int*            bin_cur    = (int*)alloc(MAXB * 4);
    unsigned short* wt1      = (unsigned short*)alloc((size_t)HID * K1 * 2);
    unsigned short* wt2      = (unsigned short*)alloc((size_t)HID * HID * 2);

    prep_kernel<<<(HID * K1 + 255) / 256, 256, 0, stream>>>(W1, W2, wt1, wt2, K1, bin_counts);

    const int ntiles = (E + TILE - 1) / TILE;
    bincount_kernel<<<ntiles, 256, 0, stream>>>(dstv, bin_counts, E, NB);
    binscan_kernel<<<1, 256, 0, stream>>>(bin_counts, bin_off, bin_cur, NB);
    stage_kernel<<<ntiles, 256, 0, stream>>>(srcv, dstv, bin_cur, pairs, E);
    binrowp_kernel<<<NB, 256, 0, stream>>>(pairs, bin_off, dinv, rowp, N, NB, E);
    fine_kernel<<<NB, 256, 0, stream>>>(pairs, bin_off, rowp, dinv, colv1, N, NB, E);

    gemm_kernel<false, 256><<<(N + 127) / 128, 256, 0, stream>>>((const void*)x, wt1, xw, N);
    agg1_kernel<<<(N + 15) / 16, 256, 0, stream>>>(xw, colv1, rowp, dinv,
                                                   b1, Wc, bc, (uint4*)h1, outp, N);
    gemm_kernel<true, 128><<<(N + 127) / 128, 256, 0, stream>>>((const void*)h1, wt2, xw, N);
    agg2_kernel<<<(N + 15) / 16, 256, 0, stream>>>(xw, (const uint4*)h1, colv1,
                                                   rowp, dinv, b2, Wf, bfv, hnode, outp, N);
}

// Round 4
// 375.828 us; speedup vs baseline: 1.1510x; 1.0339x over previous
//
#include <hip/hip_runtime.h>

// ---------------------------------------------------------------------------
// GCN 2-layer fused pipeline for MI355X (gfx950)
//   h1 = relu(Dinv (A+I) Dinv (x@W1) + b1)
//   out = 0.5*(h1@Wc + bc) + 0.5*((alpha*h2 + (1-alpha)*h1)@Wf + bf)
//   h2 = relu(Dinv (A+I) Dinv (h1@W2) + b2)
// R2: binned counting-sort CSR. R3: fused dinv into colv. R5/R6: multi-edge
// wide gathers. R8: 1-dword colv (st<<15|w15), packed f32x2 agg math.
// R10: agg one-node-per-QUARTER, depth-16 gather pipe.
// R11: gemm B in LDS (64KB) -- only 67->61us: occupancy fell to 15% (LDS cap
// 2 blocks/CU + 152 unified regs = 3 waves/SIMD); latency-bound, no TLP.
// R12: occupancy-first GEMM. 16-row waves (acc 32, A-pipe 32/16 regs),
// K-split B staging (32KB LDS/phase, 2 barriers per extra phase), B dbuf
// dropped (-32 regs; 8x ds_read issued at iter top, cvt VALU overlaps ds
// latency, compiler's fine lgkmcnt staggers the 8 MFMAs). Target ~4 waves/
// SIMD so per-iteration A/B waits are covered by co-resident waves' MFMAs.
// (R12 resubmit: previous round failed on GPU acquisition, never measured.)
// ---------------------------------------------------------------------------

#define HID 128
#define SHIFT 9
#define RANGE 512           // nodes per bin = 1<<SHIFT
#define MAXB 256            // max bins (N <= 131072)
#define TILE 4096           // edges per stage block

typedef __bf16 bf16x8 __attribute__((ext_vector_type(8)));
typedef float  f32x4  __attribute__((ext_vector_type(4)));
typedef float  f32x2  __attribute__((ext_vector_type(2)));

__device__ __forceinline__ unsigned short f2bf(float x) {
    unsigned int b = __float_as_uint(x);
    b += 0x7fffu + ((b >> 16) & 1u);     // round-to-nearest-even
    return (unsigned short)(b >> 16);
}
__device__ __forceinline__ float bflo(unsigned int u) { return __uint_as_float(u << 16); }
__device__ __forceinline__ float bfhi(unsigned int u) { return __uint_as_float(u & 0xffff0000u); }
__device__ __forceinline__ unsigned packbf(float a, float b) {
    return (unsigned)f2bf(a) | ((unsigned)f2bf(b) << 16);
}

// --------------------------- binned CSR build ------------------------------

__global__ __launch_bounds__(256)
void bincount_kernel(const int* __restrict__ dst, int* __restrict__ bin_counts,
                     int E, int NB) {
    __shared__ int h[MAXB];
    for (int i = threadIdx.x; i < NB; i += 256) h[i] = 0;
    __syncthreads();
    const int base = blockIdx.x * TILE;
#pragma unroll
    for (int j = 0; j < TILE; j += 256) {
        int e = base + j + threadIdx.x;
        if (e < E) atomicAdd(&h[((unsigned)dst[e]) >> SHIFT], 1);
    }
    __syncthreads();
    for (int i = threadIdx.x; i < NB; i += 256) {
        int v = h[i];
        if (v) atomicAdd(&bin_counts[i], v);
    }
}

__global__ void binscan_kernel(const int* __restrict__ bin_counts,
                               int* __restrict__ bin_off, int* __restrict__ bin_cur, int NB) {
    __shared__ int sh[MAXB];
    const int t = threadIdx.x;
    int v = (t < NB) ? bin_counts[t] : 0;
    sh[t] = v;
    __syncthreads();
    for (int s = 1; s < 256; s <<= 1) {
        int x = (t >= s) ? sh[t - s] : 0;
        __syncthreads();
        sh[t] += x;
        __syncthreads();
    }
    if (t < NB) {
        int ex = sh[t] - v;     // exclusive
        bin_off[t] = ex;
        bin_cur[t] = ex;
    }
}

// Block-level binning: tile-local LDS sort by bin, then bin-sorted write-out
// in contiguous runs. pairs[i] = (dlocal<<23) | src   (src < 2^23).
__global__ __launch_bounds__(256)
void stage_kernel(const int* __restrict__ src, const int* __restrict__ dst,
                  int* __restrict__ bin_cur, unsigned* __restrict__ pairs, int E) {
    __shared__ int sh_hist[MAXB];
    __shared__ int sh_off[MAXB];
    __shared__ int sh_ex[MAXB];
    __shared__ int sh_gbase[MAXB];
    __shared__ uint2 stg[TILE];
    const int t = threadIdx.x;
    const int base = blockIdx.x * TILE;
    const int cnt = min(TILE, E - base);

    for (int i = t; i < MAXB; i += 256) sh_hist[i] = 0;
    __syncthreads();

    int s[16], d[16], r[16];
#pragma unroll
    for (int j = 0; j < 16; ++j) {
        const int k = j * 256 + t;
        if (k < cnt) {
            s[j] = src[base + k];
            d[j] = dst[base + k];
            r[j] = atomicAdd(&sh_hist[((unsigned)d[j]) >> SHIFT], 1);
        }
    }
    __syncthreads();

    const int hv = sh_hist[t];
    sh_off[t] = hv;
    __syncthreads();
    for (int st = 1; st < 256; st <<= 1) {
        int x = (t >= st) ? sh_off[t - st] : 0;
        __syncthreads();
        sh_off[t] += x;
        __syncthreads();
    }
    sh_ex[t] = sh_off[t] - hv;                      // exclusive within tile
    if (hv > 0) sh_gbase[t] = atomicAdd(&bin_cur[t], hv);
    __syncthreads();

#pragma unroll
    for (int j = 0; j < 16; ++j) {
        const int k = j * 256 + t;
        if (k < cnt) {
            int b = ((unsigned)d[j]) >> SHIFT;
            stg[sh_ex[b] + r[j]] = make_uint2((unsigned)s[j], (unsigned)d[j]);
        }
    }
    __syncthreads();

    for (int i = t; i < cnt; i += 256) {
        uint2 p = stg[i];
        int b = (int)(p.y >> SHIFT);
        unsigned w = ((p.y & (RANGE - 1)) << 23) | p.x;
        pairs[sh_gbase[b] + (i - sh_ex[b])] = w;
    }
}

// Per-bin: histogram pairs -> counts; intra-bin scan (+bin_off base) -> rowp;
// dinv from counts.
__global__ __launch_bounds__(256)
void binrowp_kernel(const unsigned* __restrict__ pairs, const int* __restrict__ bin_off,
                    float* __restrict__ dinv, int* __restrict__ rowp,
                    int N, int NB, int E) {
    __shared__ int c[RANGE];
    __shared__ int sh[256];
    const int b = blockIdx.x;
    const int t = threadIdx.x;
    const int nb = b << SHIFT;
    const int nr = min(RANGE, N - nb);
    for (int i = t; i < RANGE; i += 256) c[i] = 0;
    __syncthreads();
    const int lo = bin_off[b];
    const int hi = (b + 1 < NB) ? bin_off[b + 1] : E;
    for (int i = lo + t; i < hi; i += 256)
        atomicAdd(&c[pairs[i] >> 23], 1);
    __syncthreads();
    const int v0 = c[2 * t], v1 = c[2 * t + 1];
    const int pr = v0 + v1;
    sh[t] = pr;
    __syncthreads();
    for (int s = 1; s < 256; s <<= 1) {
        int x = (t >= s) ? sh[t - s] : 0;
        __syncthreads();
        sh[t] += x;
        __syncthreads();
    }
    const int ex = sh[t] - pr + lo;     // exclusive prefix + bin edge base
    if (2 * t < nr) {
        rowp[nb + 2 * t] = ex;
        dinv[nb + 2 * t] = rsqrtf((float)(v0 + 1));
    }
    if (2 * t + 1 < nr) {
        rowp[nb + 2 * t + 1] = ex + v0;
        dinv[nb + 2 * t + 1] = rsqrtf((float)(v1 + 1));
    }
    if (b == 0 && t == 0) rowp[N] = E;
}

// Per-bin fine scatter; emits packed (src<<15)|fixed15(dinv[src])
__global__ __launch_bounds__(256)
void fine_kernel(const unsigned* __restrict__ pairs, const int* __restrict__ bin_off,
                 const int* __restrict__ rowp, const float* __restrict__ dinv,
                 unsigned* __restrict__ colv1, int N, int NB, int E) {
    __shared__ int cur[RANGE];
    const int b = blockIdx.x;
    const int nb = b << SHIFT;
    const int nr = min(RANGE, N - nb);
    for (int i = threadIdx.x; i < nr; i += 256) cur[i] = rowp[nb + i];
    __syncthreads();
    const int lo = bin_off[b];
    const int hi = (b + 1 < NB) ? bin_off[b + 1] : E;
    for (int i = lo + threadIdx.x; i < hi; i += 256) {
        unsigned w = pairs[i];
        unsigned s = w & 0x7fffffu;
        int pos = atomicAdd(&cur[w >> 23], 1);
        unsigned w15 = __float2uint_rn(dinv[s] * 32767.0f);   // dinv in (0,1]
        colv1[pos] = (s << 15) | w15;
    }
}

// Merged prep: zero bin_counts + both weight transposes (Wt[col][k] bf16)
__global__ void prep_kernel(const float* __restrict__ W1, const float* __restrict__ W2,
                            unsigned short* __restrict__ wt1, unsigned short* __restrict__ wt2,
                            int K1, int* __restrict__ bin_counts) {
    int idx = blockIdx.x * 256 + threadIdx.x;
    if (idx < MAXB) bin_counts[idx] = 0;
    if (idx < 128 * K1) {
        int nn = idx / K1, k = idx - nn * K1;
        wt1[(size_t)nn * K1 + k] = f2bf(W1[(size_t)k * 128 + nn]);
    }
    if (idx < 128 * 128) {
        int nn = idx >> 7, k = idx & 127;
        wt2[(size_t)nn * 128 + k] = f2bf(W2[(size_t)k * 128 + nn]);
    }
}

// ------------------------------- GEMM --------------------------------------
// Out[row][col] (bf16, N x 128) = A (N x K) @ W, via Wt[col][k] bf16.
// R12 structure: 16-row waves (one 16x16 MFMA row-tile, 64 rows/block).
// B staged to LDS in K-phases of 128 (32KB; K=256 runs 2 phases, 2 extra
// barriers). Per iteration: 8x ds_read_b128 B fragments (no double-buffer;
// fine-grained lgkmcnt staggers the MFMAs), fp32->bf16 cvt of the oldest
// A-pipe slot overlaps the ds latency, A refill keeps DEPTH=4 slots in
// flight on vmcnt. Swizzle: chunk kc stored at kc ^ (col & (CHH-1)).
template <bool A_BF16, int K>
__global__ __launch_bounds__(256)
void gemm_kernel(const void* __restrict__ Aptr, const unsigned short* __restrict__ Wt,
                 unsigned short* __restrict__ Out, int nrows) {
    constexpr int NIT  = K / 32;
    constexpr int DEPTH = (NIT < 4) ? NIT : 4;
    constexpr int HK   = (K > 128) ? (K / 2) : K;   // K staged per phase
    constexpr int CHH  = HK / 8;                    // 16B chunks per col/phase
    constexpr int PH   = K / HK;
    constexpr int NITP = HK / 32;
    __shared__ uint4 sB[128 * CHH];                 // 32 KB

    const int tid  = threadIdx.x;
    const int wave = tid >> 6;
    const int lane = tid & 63;
    const int q = lane >> 4;
    const int r = lane & 15;

    const int wrow = blockIdx.x * 64 + wave * 16;
    const size_t row0 = (size_t)min(wrow + r, nrows - 1);

    const unsigned short* A16 = (const unsigned short*)Aptr;
    const float*          A32 = (const float*)Aptr;

    f32x4 acc[8];
#pragma unroll
    for (int c = 0; c < 8; ++c) acc[c] = (f32x4){0.f, 0.f, 0.f, 0.f};

    bf16x8 preb[DEPTH];
    float4 pref[DEPTH][2];

    // prologue: fill the A pipe
#pragma unroll
    for (int i = 0; i < DEPTH; ++i) {
        const int kk = i * 32 + q * 8;
        if (A_BF16) {
            preb[i] = *reinterpret_cast<const bf16x8*>(A16 + row0 * K + kk);
        } else {
            pref[i][0] = *reinterpret_cast<const float4*>(A32 + row0 * K + kk);
            pref[i][1] = *reinterpret_cast<const float4*>(A32 + row0 * K + kk + 4);
        }
    }

#pragma unroll
    for (int ph = 0; ph < PH; ++ph) {
        if (ph) __syncthreads();
        // stage this phase's B half (coalesced; swizzled chunk placement)
        for (int idx = tid; idx < 128 * CHH; idx += 256) {
            const int col = idx / CHH;
            const int kc  = idx & (CHH - 1);
            const uint4 v = *reinterpret_cast<const uint4*>(
                Wt + (size_t)col * K + ph * HK + kc * 8);
            sB[col * CHH + (kc ^ (col & (CHH - 1)))] = v;
        }
        __syncthreads();

#pragma unroll
        for (int itp = 0; itp < NITP; ++itp) {
            const int git  = ph * NITP + itp;
            const int slot = git % DEPTH;

            // B fragments for this K-step from swizzled LDS
            bf16x8 bcur[8];
#pragma unroll
            for (int c = 0; c < 8; ++c) {
                const int col = c * 16 + r;
                const int chunk = (itp * 4 + q) ^ (col & (CHH - 1));
                bcur[c] = *reinterpret_cast<const bf16x8*>(&sB[col * CHH + chunk]);
            }

            // consume oldest A slot (vmcnt waits only on A pipe); cvt VALU
            // work overlaps the ds_read latency of bcur
            bf16x8 afrag;
            if (A_BF16) {
                afrag = preb[slot];
            } else {
                const float4 x0 = pref[slot][0];
                const float4 x1 = pref[slot][1];
                bf16x8 a;
                a[0] = (__bf16)x0.x; a[1] = (__bf16)x0.y; a[2] = (__bf16)x0.z; a[3] = (__bf16)x0.w;
                a[4] = (__bf16)x1.x; a[5] = (__bf16)x1.y; a[6] = (__bf16)x1.z; a[7] = (__bf16)x1.w;
                afrag = a;
            }

            // refill the pipe slot (stays in flight across iterations)
            if (git + DEPTH < NIT) {
                const int kk2 = (git + DEPTH) * 32 + q * 8;
                if (A_BF16) {
                    preb[slot] = *reinterpret_cast<const bf16x8*>(A16 + row0 * K + kk2);
                } else {
                    pref[slot][0] = *reinterpret_cast<const float4*>(A32 + row0 * K + kk2);
                    pref[slot][1] = *reinterpret_cast<const float4*>(A32 + row0 * K + kk2 + 4);
                }
            }

#pragma unroll
            for (int c = 0; c < 8; ++c)
                acc[c] = __builtin_amdgcn_mfma_f32_16x16x32_bf16(afrag, bcur[c], acc[c], 0, 0, 0);
        }
    }

#pragma unroll
    for (int v = 0; v < 4; ++v) {
        const int row = wrow + q * 4 + v;
        if (row < nrows) {
#pragma unroll
            for (int c = 0; c < 8; ++c)
                Out[(size_t)row * 128 + c * 16 + r] = f2bf(acc[c][v]);
        }
    }
}

// --------------------------- Aggregation -----------------------------------
// R10: one node per 16-lane QUARTER (4 nodes/wave, 16 nodes/block). Lane
// c=lane&15 owns features 8c..8c+7 (one uint4 = 16B of the 256B row). Per
// 16-edge chunk: issue ALL 16 gathers per lane (depth-16 pipeline, pf[16]),
// prefetch next chunk's colv word, then consume into f32x2 accumulators
// (v_pk_fma). Quarter-local shfl_xor(1,2,4,8) reduction for the 2-wide
// logits; no cross-quarter merges, no duplicated epilogue.
// Tail lanes (j >= valid count) carry cw=0 -> row 0 gathered with weight 0:
// branchless and harmless (guards only at 4-edge group granularity).

#define AGG_ISSUE(g, TBL)                                                     \
    if ((g) * 4 < cnt) {                                                      \
        _Pragma("unroll")                                                     \
        for (int j = 0; j < 4; ++j) {                                         \
            const int sl = (g) * 4 + j;                                       \
            const unsigned cg = (unsigned)__shfl((int)cw, qb + sl);           \
            wt[sl] = (float)(cg & 0x7fffu) * (1.0f / 32767.0f);               \
            pf[sl] = *reinterpret_cast<const uint4*>(                         \
                (const char*)(TBL) + (((cg >> 15) << 8) + coff));             \
        }                                                                     \
    }

#define AGG_CONS(g)                                                          \
    if ((g) * 4 < cnt) {                                                     \
        _Pragma("unroll")                                                    \
        for (int j = 0; j < 4; ++j) {                                        \
            const int sl = (g) * 4 + j;                                      \
            const float w = wt[sl];                                          \
            const uint4 uu = pf[sl];                                         \
            A0 += (f32x2){bflo(uu.x), bfhi(uu.x)} * w;                       \
            A1 += (f32x2){bflo(uu.y), bfhi(uu.y)} * w;                       \
            A2 += (f32x2){bflo(uu.z), bfhi(uu.z)} * w;                       \
            A3 += (f32x2){bflo(uu.w), bfhi(uu.w)} * w;                       \
        }                                                                    \
    }

#define AGG_EDGE_LOOP(TBL)                                                   \
    unsigned cw = (beg + c < end) ? colv1[beg + c] : 0u;                     \
    for (int base = beg; base < end; base += 16) {                           \
        const int cnt = end - base;                                          \
        AGG_ISSUE(0, TBL) AGG_ISSUE(1, TBL) AGG_ISSUE(2, TBL) AGG_ISSUE(3, TBL) \
        unsigned cw_next = 0u;                                               \
        if (base + 16 + c < end) cw_next = colv1[base + 16 + c];             \
        AGG_CONS(0) AGG_CONS(1) AGG_CONS(2) AGG_CONS(3)                      \
        cw = cw_next;                                                        \
    }

__device__ __forceinline__ f32x2 __shfl_xor(f32x2 v, int m) {
    return (f32x2){__shfl_xor(v[0], m), __shfl_xor(v[1], m)};
}

__global__ __launch_bounds__(256)
void agg1_kernel(const unsigned short* __restrict__ xw, const unsigned* __restrict__ colv1,
                 const int* __restrict__ rowp, const float* __restrict__ dinv,
                 const float* __restrict__ b1, const float* __restrict__ Wc,
                 const float* __restrict__ bc, uint4* __restrict__ h1,
                 float* __restrict__ outp, int n) {
    const int node = blockIdx.x * 16 + (threadIdx.x >> 4);
    if (node >= n) return;
    const int lane = threadIdx.x & 63;
    const int c    = lane & 15;
    const int qb   = lane & 48;               // quarter base lane
    const unsigned coff = (unsigned)c << 4;
    const float di = dinv[node];
    const int beg = rowp[node], end = rowp[node + 1];

    // self-loop row: issued now, consumed after the edge loop
    const uint4 su = *reinterpret_cast<const uint4*>(
        (const char*)xw + (((unsigned)node << 8) + coff));

    f32x2 A0 = {0.f,0.f}, A1 = {0.f,0.f}, A2 = {0.f,0.f}, A3 = {0.f,0.f};
    uint4 pf[16];
    float wt[16];

    AGG_EDGE_LOOP(xw)

    A0 += (f32x2){bflo(su.x), bfhi(su.x)} * di;
    A1 += (f32x2){bflo(su.y), bfhi(su.y)} * di;
    A2 += (f32x2){bflo(su.z), bfhi(su.z)} * di;
    A3 += (f32x2){bflo(su.w), bfhi(su.w)} * di;

    const float4 bb0 = reinterpret_cast<const float4*>(b1)[2*c];
    const float4 bb1 = reinterpret_cast<const float4*>(b1)[2*c + 1];
    float a0 = fmaxf(A0[0]*di + bb0.x, 0.f), a1 = fmaxf(A0[1]*di + bb0.y, 0.f);
    float a2 = fmaxf(A1[0]*di + bb0.z, 0.f), a3 = fmaxf(A1[1]*di + bb0.w, 0.f);
    float a4 = fmaxf(A2[0]*di + bb1.x, 0.f), a5 = fmaxf(A2[1]*di + bb1.y, 0.f);
    float a6 = fmaxf(A3[0]*di + bb1.z, 0.f), a7 = fmaxf(A3[1]*di + bb1.w, 0.f);

    h1[((unsigned)node << 4) + c] =
        make_uint4(packbf(a0,a1), packbf(a2,a3), packbf(a4,a5), packbf(a6,a7));

    const float4 w0 = reinterpret_cast<const float4*>(Wc)[4*c];
    const float4 w1 = reinterpret_cast<const float4*>(Wc)[4*c + 1];
    const float4 w2 = reinterpret_cast<const float4*>(Wc)[4*c + 2];
    const float4 w3 = reinterpret_cast<const float4*>(Wc)[4*c + 3];
    float c0 = a0*w0.x + a1*w0.z + a2*w1.x + a3*w1.z
             + a4*w2.x + a5*w2.z + a6*w3.x + a7*w3.z;
    float c1 = a0*w0.y + a1*w0.w + a2*w1.y + a3*w1.w
             + a4*w2.y + a5*w2.w + a6*w3.y + a7*w3.w;
#pragma unroll
    for (int off = 1; off < 16; off <<= 1) {       // quarter-local reduce
        c0 += __shfl_xor(c0, off);
        c1 += __shfl_xor(c1, off);
    }
    if (c == 0) {
        outp[2 * (size_t)node]     = 0.5f * (c0 + bc[0]);
        outp[2 * (size_t)node + 1] = 0.5f * (c1 + bc[1]);
    }
}

__global__ __launch_bounds__(256)
void agg2_kernel(const unsigned short* __restrict__ xw2, const uint4* __restrict__ h1,
                 const unsigned* __restrict__ colv1, const int* __restrict__ rowp,
                 const float* __restrict__ dinv, const float* __restrict__ b2,
                 const float* __restrict__ Wf, const float* __restrict__ bfv,
                 const float* __restrict__ hnode, float* __restrict__ outp, int n) {
    const int node = blockIdx.x * 16 + (threadIdx.x >> 4);
    if (node >= n) return;
    const int lane = threadIdx.x & 63;
    const int c    = lane & 15;
    const int qb   = lane & 48;
    const unsigned coff = (unsigned)c << 4;
    const float di = dinv[node];
    const int beg = rowp[node], end = rowp[node + 1];

    const uint4 su = *reinterpret_cast<const uint4*>(
        (const char*)xw2 + (((unsigned)node << 8) + coff));

    f32x2 A0 = {0.f,0.f}, A1 = {0.f,0.f}, A2 = {0.f,0.f}, A3 = {0.f,0.f};
    uint4 pf[16];
    float wt[16];

    AGG_EDGE_LOOP(xw2)

    A0 += (f32x2){bflo(su.x), bfhi(su.x)} * di;
    A1 += (f32x2){bflo(su.y), bfhi(su.y)} * di;
    A2 += (f32x2){bflo(su.z), bfhi(su.z)} * di;
    A3 += (f32x2){bflo(su.w), bfhi(su.w)} * di;

    const float4 bb0 = reinterpret_cast<const float4*>(b2)[2*c];
    const float4 bb1 = reinterpret_cast<const float4*>(b2)[2*c + 1];
    float h20 = fmaxf(A0[0]*di + bb0.x, 0.f), h21 = fmaxf(A0[1]*di + bb0.y, 0.f);
    float h22 = fmaxf(A1[0]*di + bb0.z, 0.f), h23 = fmaxf(A1[1]*di + bb0.w, 0.f);
    float h24 = fmaxf(A2[0]*di + bb1.x, 0.f), h25 = fmaxf(A2[1]*di + bb1.y, 0.f);
    float h26 = fmaxf(A3[0]*di + bb1.z, 0.f), h27 = fmaxf(A3[1]*di + bb1.w, 0.f);

    const float alpha = hnode[node];
    const float beta  = 1.f - alpha;
    const uint4 hh = h1[((unsigned)node << 4) + c];
    const float ha0 = alpha*h20 + beta*bflo(hh.x);
    const float ha1 = alpha*h21 + beta*bfhi(hh.x);
    const float ha2 = alpha*h22 + beta*bflo(hh.y);
    const float ha3 = alpha*h23 + beta*bfhi(hh.y);
    const float ha4 = alpha*h24 + beta*bflo(hh.z);
    const float ha5 = alpha*h25 + beta*bfhi(hh.z);
    const float ha6 = alpha*h26 + beta*bflo(hh.w);
    const float ha7 = alpha*h27 + beta*bfhi(hh.w);

    const float4 w0 = reinterpret_cast<const float4*>(Wf)[4*c];
    const float4 w1 = reinterpret_cast<const float4*>(Wf)[4*c + 1];
    const float4 w2 = reinterpret_cast<const float4*>(Wf)[4*c + 2];
    const float4 w3 = reinterpret_cast<const float4*>(Wf)[4*c + 3];
    float f0 = ha0*w0.x + ha1*w0.z + ha2*w1.x + ha3*w1.z
             + ha4*w2.x + ha5*w2.z + ha6*w3.x + ha7*w3.z;
    float f1 = ha0*w0.y + ha1*w0.w + ha2*w1.y + ha3*w1.w
             + ha4*w2.y + ha5*w2.w + ha6*w3.y + ha7*w3.w;
#pragma unroll
    for (int off = 1; off < 16; off <<= 1) {
        f0 += __shfl_xor(f0, off);
        f1 += __shfl_xor(f1, off);
    }
    if (c == 0) {
        outp[2 * (size_t)node]     += 0.5f * (f0 + bfv[0]);
        outp[2 * (size_t)node + 1] += 0.5f * (f1 + bfv[1]);
    }
}

// ------------------------------ launch -------------------------------------

extern "C" void kernel_launch(void* const* d_in, const int* in_sizes, int n_in,
                              void* d_out, int out_size, void* d_ws, size_t ws_size,
                              hipStream_t stream) {
    const float* x     = (const float*)d_in[0];
    const int*   ei    = (const int*)d_in[1];     // int32 per harness contract
    const float* hnode = (const float*)d_in[2];
    const float* W1    = (const float*)d_in[3];
    const float* b1    = (const float*)d_in[4];
    const float* W2    = (const float*)d_in[5];
    const float* b2    = (const float*)d_in[6];
    const float* Wc    = (const float*)d_in[7];
    const float* bc    = (const float*)d_in[8];
    const float* Wf    = (const float*)d_in[9];
    const float* bfv   = (const float*)d_in[10];

    const int N  = in_sizes[2];
    const int E  = in_sizes[1] / 2;
    const int K1 = in_sizes[3] / HID;   // 256 (fixed by problem shape)
    const int NB = (N + RANGE - 1) >> SHIFT;
    const int* srcv = ei;
    const int* dstv = ei + E;
    float* outp = (float*)d_out;

    char* ws = (char*)d_ws;
    size_t off = 0;
    auto alloc = [&](size_t bytes) -> char* {
        char* p = ws + off;
        off += (bytes + 255) & ~(size_t)255;
        return p;
    };
    unsigned short* xw       = (unsigned short*)alloc((size_t)N * HID * 2);  // 25.6 MB
    unsigned short* h1       = (unsigned short*)alloc((size_t)N * HID * 2);  // 25.6 MB
    float*          dinv     = (float*)alloc((size_t)N * 4);
    int*            rowp     = (int*)alloc((size_t)(N + 1) * 4);
    unsigned*       colv1    = (unsigned*)alloc((size_t)E * 4);              // 6.4 MB
    unsigned*       pairs    = (unsigned*)alloc((size_t)E * 4);              // 6.4 MB
    int*            bin_counts = (int*)alloc(MAXB * 4);
    int*            bin_off    = (int*)alloc(MAXB * 4);
    int*            bin_cur    = (int*)alloc(MAXB * 4);
    unsigned short* wt1      = (unsigned short*)alloc((size_t)HID * K1 * 2);
    unsigned short* wt2      = (unsigned short*)alloc((size_t)HID * HID * 2);

    prep_kernel<<<(HID * K1 + 255) / 256, 256, 0, stream>>>(W1, W2, wt1, wt2, K1, bin_counts);

    const int ntiles = (E + TILE - 1) / TILE;
    bincount_kernel<<<ntiles, 256, 0, stream>>>(dstv, bin_counts, E, NB);
    binscan_kernel<<<1, 256, 0, stream>>>(bin_counts, bin_off, bin_cur, NB);
    stage_kernel<<<ntiles, 256, 0, stream>>>(srcv, dstv, bin_cur, pairs, E);
    binrowp_kernel<<<NB, 256, 0, stream>>>(pairs, bin_off, dinv, rowp, N, NB, E);
    fine_kernel<<<NB, 256, 0, stream>>>(pairs, bin_off, rowp, dinv, colv1, N, NB, E);

    gemm_kernel<false, 256><<<(N + 63) / 64, 256, 0, stream>>>((const void*)x, wt1, xw, N);
    agg1_kernel<<<(N + 15) / 16, 256, 0, stream>>>(xw, colv1, rowp, dinv,
                                                   b1, Wc, bc, (uint4*)h1, outp, N);
    gemm_kernel<true, 128><<<(N + 63) / 64, 256, 0, stream>>>((const void*)h1, wt2, xw, N);
    agg2_kernel<<<(N + 15) / 16, 256, 0, stream>>>(xw, (const uint4*)h1, colv1,
                                                   rowp, dinv, b2, Wf, bfv, hnode, outp, N);
}